// Round 19
// baseline (453.612 us; speedup 1.0000x reference)
//
#include <hip/hip_runtime.h>
#include <hip/hip_bf16.h>
#include <cstdint>

typedef __attribute__((ext_vector_type(4))) float f32x4;
typedef __attribute__((ext_vector_type(8))) short bf16x8;

__device__ __forceinline__ unsigned short f2bf(float f){
  union { float f; unsigned int u; } v; v.f = f;
  unsigned int u = v.u;
  u += 0x7FFFu + ((u >> 16) & 1u);   // round-to-nearest-even
  return (unsigned short)(u >> 16);
}
__device__ __forceinline__ float bf2f(unsigned short s){
  union { unsigned int u; float f; } v; v.u = ((unsigned int)s) << 16;
  return v.f;
}

// ---------------------------------------------------------------- cvt f32->bf16
__global__ __launch_bounds__(256) void cvt_bf16(const float* __restrict__ in,
                                                unsigned short* __restrict__ out,
                                                int n4){
  int i = blockIdx.x * 256 + threadIdx.x;
  if (i < n4){
    float4 v = ((const float4*)in)[i];
    ushort4 o;
    o.x = f2bf(v.x); o.y = f2bf(v.y); o.z = f2bf(v.z); o.w = f2bf(v.w);
    ((ushort4*)out)[i] = o;
  }
}

// ---------------------------------------------------------------- fused QKV GEMM
// widx 0 -> Q row-major; widx 1 -> Khead[bh][key][64]; widx 2 -> Vt[(b*1024+col)][s]
__global__ __launch_bounds__(256) void qkv_gemm(
    const unsigned short* __restrict__ A,
    const unsigned short* __restrict__ W0,
    const unsigned short* __restrict__ W1,
    const unsigned short* __restrict__ W2,
    const float* __restrict__ b0,
    const float* __restrict__ b1,
    const float* __restrict__ b2,
    unsigned short* __restrict__ Qo,
    unsigned short* __restrict__ Khead,
    unsigned short* __restrict__ Vto)
{
  __shared__ unsigned short As[2][128*64];
  __shared__ unsigned short Bs[2][128*64];

  const int K = 1024;
  const int tid = threadIdx.x;
  const int l   = tid & 63;
  const int wid = tid >> 6;
  const int g   = l >> 4;
  const int li  = l & 15;
  const int widx = blockIdx.x >> 3;
  const int m0  = blockIdx.y * 128;
  const int n0  = (blockIdx.x & 7) * 128;
  const int wm  = (wid >> 1) * 64;
  const int wn  = (wid & 1) * 64;
  const int srow = tid >> 3;
  const int sck  = tid & 7;

  const unsigned short* Bw = (widx == 0) ? W0 : ((widx == 1) ? W1 : W2);
  const float* bias        = (widx == 0) ? b0 : ((widx == 1) ? b1 : b2);

  const unsigned short* Ag = A  + (size_t)(m0 + srow) * K + sck * 8;
  const unsigned short* Bg = Bw + (size_t)(n0 + srow) * K + sck * 8;

  f32x4 acc[4][4] = {};
  bf16x8 ra[4], rb[4];
  const int NT = K >> 6;

  #pragma unroll
  for (int r = 0; r < 4; ++r){
    ra[r] = *(const bf16x8*)(Ag + (size_t)(r*32) * K);
    rb[r] = *(const bf16x8*)(Bg + (size_t)(r*32) * K);
  }
  #pragma unroll
  for (int r = 0; r < 4; ++r){
    const int row = srow + r*32;
    const int ck  = sck ^ (row & 7);
    *(bf16x8*)(&As[0][row*64 + ck*8]) = ra[r];
    *(bf16x8*)(&Bs[0][row*64 + ck*8]) = rb[r];
  }
  __syncthreads();

  int cur = 0;
  for (int kt = 0; kt < NT; ++kt){
    if (kt + 1 < NT){
      const int kof = (kt + 1) << 6;
      #pragma unroll
      for (int r = 0; r < 4; ++r){
        ra[r] = *(const bf16x8*)(Ag + (size_t)(r*32) * K + kof);
        rb[r] = *(const bf16x8*)(Bg + (size_t)(r*32) * K + kof);
      }
    }
    #pragma unroll
    for (int kk = 0; kk < 2; ++kk){
      bf16x8 af[4], bfr[4];
      #pragma unroll
      for (int f = 0; f < 4; ++f){
        const int rowa = wm + f*16 + li;
        const int cka  = (kk*4 + g) ^ (rowa & 7);
        af[f] = *(const bf16x8*)(&As[cur][rowa*64 + cka*8]);
        const int rowb = wn + f*16 + li;
        const int ckb  = (kk*4 + g) ^ (rowb & 7);
        bfr[f] = *(const bf16x8*)(&Bs[cur][rowb*64 + ckb*8]);
      }
      #pragma unroll
      for (int fm = 0; fm < 4; ++fm)
        #pragma unroll
        for (int fn = 0; fn < 4; ++fn)
          acc[fm][fn] = __builtin_amdgcn_mfma_f32_16x16x32_bf16(af[fm], bfr[fn], acc[fm][fn], 0, 0, 0);
    }
    __syncthreads();
    if (kt + 1 < NT){
      #pragma unroll
      for (int r = 0; r < 4; ++r){
        const int row = srow + r*32;
        const int ck  = sck ^ (row & 7);
        *(bf16x8*)(&As[cur^1][row*64 + ck*8]) = ra[r];
        *(bf16x8*)(&Bs[cur^1][row*64 + ck*8]) = rb[r];
      }
      __syncthreads();
    }
    cur ^= 1;
  }

  #pragma unroll
  for (int fn = 0; fn < 4; ++fn){
    const int col = n0 + wn + fn*16 + li;
    const float bv = bias[col];
    #pragma unroll
    for (int fm = 0; fm < 4; ++fm){
      #pragma unroll
      for (int j = 0; j < 4; ++j){
        const int row = m0 + wm + fm*16 + g*4 + j;
        const float v = acc[fm][fn][j] + bv;
        const int bb = row >> 11;
        const int s  = row & 2047;
        if (widx == 0){
          Qo[(size_t)row * 1024 + col] = f2bf(v);
        } else if (widx == 1){
          const int hh = col >> 6, dd = col & 63;
          Khead[(((size_t)(bb*16 + hh))*2048 + s)*64 + dd] = f2bf(v);
        } else {
          Vto[((size_t)(bb*1024 + col)) * 2048 + s] = f2bf(v);
        }
      }
    }
  }
}

// ---------------------------------------------------------------- out-proj GEMM (f32 out)
__global__ __launch_bounds__(256) void gemm_bt(
    const unsigned short* __restrict__ A,
    const unsigned short* __restrict__ Bw,
    const float* __restrict__ bias,
    float* __restrict__ outp,
    int M, int N, int K)
{
  __shared__ unsigned short As[2][128*64];
  __shared__ unsigned short Bs[2][128*64];

  const int tid = threadIdx.x;
  const int l   = tid & 63;
  const int wid = tid >> 6;
  const int g   = l >> 4;
  const int li  = l & 15;
  const int m0  = blockIdx.y * 128;
  const int n0  = blockIdx.x * 128;
  const int wm  = (wid >> 1) * 64;
  const int wn  = (wid & 1) * 64;
  const int srow = tid >> 3;
  const int sck  = tid & 7;

  const unsigned short* Ag = A  + (size_t)(m0 + srow) * K + sck * 8;
  const unsigned short* Bg = Bw + (size_t)(n0 + srow) * K + sck * 8;

  f32x4 acc[4][4] = {};
  bf16x8 ra[4], rb[4];
  const int NT = K >> 6;

  #pragma unroll
  for (int r = 0; r < 4; ++r){
    ra[r] = *(const bf16x8*)(Ag + (size_t)(r*32) * K);
    rb[r] = *(const bf16x8*)(Bg + (size_t)(r*32) * K);
  }
  #pragma unroll
  for (int r = 0; r < 4; ++r){
    const int row = srow + r*32;
    const int ck  = sck ^ (row & 7);
    *(bf16x8*)(&As[0][row*64 + ck*8]) = ra[r];
    *(bf16x8*)(&Bs[0][row*64 + ck*8]) = rb[r];
  }
  __syncthreads();

  int cur = 0;
  for (int kt = 0; kt < NT; ++kt){
    if (kt + 1 < NT){
      const int kof = (kt + 1) << 6;
      #pragma unroll
      for (int r = 0; r < 4; ++r){
        ra[r] = *(const bf16x8*)(Ag + (size_t)(r*32) * K + kof);
        rb[r] = *(const bf16x8*)(Bg + (size_t)(r*32) * K + kof);
      }
    }
    #pragma unroll
    for (int kk = 0; kk < 2; ++kk){
      bf16x8 af[4], bfr[4];
      #pragma unroll
      for (int f = 0; f < 4; ++f){
        const int rowa = wm + f*16 + li;
        const int cka  = (kk*4 + g) ^ (rowa & 7);
        af[f] = *(const bf16x8*)(&As[cur][rowa*64 + cka*8]);
        const int rowb = wn + f*16 + li;
        const int ckb  = (kk*4 + g) ^ (rowb & 7);
        bfr[f] = *(const bf16x8*)(&Bs[cur][rowb*64 + ckb*8]);
      }
      #pragma unroll
      for (int fm = 0; fm < 4; ++fm)
        #pragma unroll
        for (int fn = 0; fn < 4; ++fn)
          acc[fm][fn] = __builtin_amdgcn_mfma_f32_16x16x32_bf16(af[fm], bfr[fn], acc[fm][fn], 0, 0, 0);
    }
    __syncthreads();
    if (kt + 1 < NT){
      #pragma unroll
      for (int r = 0; r < 4; ++r){
        const int row = srow + r*32;
        const int ck  = sck ^ (row & 7);
        *(bf16x8*)(&As[cur^1][row*64 + ck*8]) = ra[r];
        *(bf16x8*)(&Bs[cur^1][row*64 + ck*8]) = rb[r];
      }
      __syncthreads();
    }
    cur ^= 1;
  }

  #pragma unroll
  for (int fn = 0; fn < 4; ++fn){
    const int col = n0 + wn + fn*16 + li;
    const float bv = bias[col];
    #pragma unroll
    for (int fm = 0; fm < 4; ++fm){
      #pragma unroll
      for (int j = 0; j < 4; ++j){
        const int row = m0 + wm + fm*16 + g*4 + j;
        outp[(size_t)row * N + col] = acc[fm][fn][j] + bv;
      }
    }
  }
}

// ---------------------------------------------------------------- attn_ind (R19)
// BARRIER-FREE attention: 4 fully independent waves per 256-thread block, each owns
// 16 q-rows over all 2048 keys. K read directly from head-contiguous Khead (coalesced,
// L2-hot, no LDS staging). Private per-wave 8KB LDS P slab (same-wave deps only).
// Pass A: denominators in registers. Pass B per tile: QK^T -> normalized bf16 P ->
// PV (batched V) -> 16 NT stores streamed per wave. Zero __syncthreads / s_barrier.
__global__ __launch_bounds__(256, 3) void attn_ind(
    const unsigned short* __restrict__ Qb,    // [4096][1024] bf16
    const unsigned short* __restrict__ Khead, // [32][2048][64] bf16
    const unsigned short* __restrict__ Vt,    // [2048][2048] bf16
    float* __restrict__ attn,                 // [32][2048][2048] f32
    unsigned short* __restrict__ ctxb)        // [4096][1024] bf16
{
  __shared__ __align__(16) unsigned short Pw4[4][16*256];   // 32 KB: private P slabs

  const int tid = threadIdx.x;
  const int l   = tid & 63;
  const int w   = tid >> 6;       // 0..3, independent wave
  const int g   = l >> 4;
  const int li  = l & 15;
  const int bh  = blockIdx.x & 31;    // same-bh blocks adjacent -> shared K/V in L2
  const int qt  = blockIdx.x >> 5;    // 0..31
  const int b   = bh >> 4;
  const int h   = bh & 15;

  const int qrow = qt*64 + w*16 + li;
  const size_t qoff = (size_t)(b*2048 + qrow) * 1024 + h*64 + g*8;
  const bf16x8 aq0 = *(const bf16x8*)(Qb + qoff);
  const bf16x8 aq1 = *(const bf16x8*)(Qb + qoff + 32);
  const unsigned short* Kg0 = Khead + (size_t)bh * (2048*64) + g*8;

  // ---- pass A: denominators (no LDS, no barriers; 16 loads in flight per half)
  float ls = 0.f;
  for (int kt = 0; kt < 8; ++kt){
    #pragma unroll
    for (int half = 0; half < 2; ++half){
      bf16x8 bk[16];
      #pragma unroll
      for (int cf = 0; cf < 8; ++cf){
        const unsigned short* kr = Kg0 + (size_t)(kt*256 + half*128 + cf*16 + li) * 64;
        bk[cf*2]   = *(const bf16x8*)(kr);
        bk[cf*2+1] = *(const bf16x8*)(kr + 32);
      }
      #pragma unroll
      for (int cf = 0; cf < 8; ++cf){
        f32x4 t = {};
        t = __builtin_amdgcn_mfma_f32_16x16x32_bf16(bk[cf*2],   aq0, t, 0, 0, 0);
        t = __builtin_amdgcn_mfma_f32_16x16x32_bf16(bk[cf*2+1], aq1, t, 0, 0, 0);
        ls += __expf(t[0]*0.125f) + __expf(t[1]*0.125f)
            + __expf(t[2]*0.125f) + __expf(t[3]*0.125f);
      }
    }
  }
  ls += __shfl_xor(ls, 16);
  ls += __shfl_xor(ls, 32);
  const float rv = 1.0f / ls;          // 1/denom for q-row = li

  // ---- pass B: recompute, P -> private LDS slab, PV, streamed NT stores
  f32x4 pv[4] = {};
  char* myP = (char*)(&Pw4[w][0]);     // 16 rows x 512B
  const int swz = (li & 7) << 3;
  const unsigned short* Vb0 = Vt + (size_t)(b*1024 + h*64) * 2048;
  float* arow0 = attn + ((size_t)bh*2048 + qt*64 + w*16) * 2048;

  for (int kt = 0; kt < 8; ++kt){
    // QK^T -> normalized bf16 P (private slab, same-wave dependency only)
    #pragma unroll
    for (int half = 0; half < 2; ++half){
      bf16x8 bk[16];
      #pragma unroll
      for (int cf = 0; cf < 8; ++cf){
        const unsigned short* kr = Kg0 + (size_t)(kt*256 + half*128 + cf*16 + li) * 64;
        bk[cf*2]   = *(const bf16x8*)(kr);
        bk[cf*2+1] = *(const bf16x8*)(kr + 32);
      }
      #pragma unroll
      for (int cf = 0; cf < 8; ++cf){
        f32x4 t = {};
        t = __builtin_amdgcn_mfma_f32_16x16x32_bf16(bk[cf*2],   aq0, t, 0, 0, 0);
        t = __builtin_amdgcn_mfma_f32_16x16x32_bf16(bk[cf*2+1], aq1, t, 0, 0, 0);
        ushort4 u;
        u.x = f2bf(__expf(t[0]*0.125f) * rv);
        u.y = f2bf(__expf(t[1]*0.125f) * rv);
        u.z = f2bf(__expf(t[2]*0.125f) * rv);
        u.w = f2bf(__expf(t[3]*0.125f) * rv);
        const int colb = half*256 + cf*32 + g*8;   // byte col = key*2 within tile
        *(ushort4*)(myP + li*512 + (colb ^ swz)) = u;
      }
    }

    // PV: 2 halves x (16 batched V loads; 4 key-steps x 4 d-frags)
    #pragma unroll
    for (int vh = 0; vh < 2; ++vh){
      bf16x8 vb[16];
      #pragma unroll
      for (int ks = 0; ks < 4; ++ks)
        #pragma unroll
        for (int df = 0; df < 4; ++df)
          vb[ks*4+df] = *(const bf16x8*)(Vb0 + (size_t)(df*16 + li)*2048
                                         + kt*256 + (vh*4+ks)*32 + g*8);
      #pragma unroll
      for (int ks = 0; ks < 4; ++ks){
        const int colb = (vh*4+ks)*64 + g*16;
        const ushort4 plo = *(const ushort4*)(myP + li*512 + ( colb      ^ swz));
        const ushort4 phi = *(const ushort4*)(myP + li*512 + ((colb + 8) ^ swz));
        bf16x8 pa;
        pa[0] = plo.x; pa[1] = plo.y; pa[2] = plo.z; pa[3] = plo.w;
        pa[4] = phi.x; pa[5] = phi.y; pa[6] = phi.z; pa[7] = phi.w;
        #pragma unroll
        for (int df = 0; df < 4; ++df)
          pv[df] = __builtin_amdgcn_mfma_f32_16x16x32_bf16(pa, vb[ks*4+df], pv[df], 0, 0, 0);
      }
    }

    // attn stores: coalesced readback, 16 x 1KB NT, streamed (no barrier follows)
    #pragma unroll
    for (int r = 0; r < 16; ++r){
      const ushort4 u = *(const ushort4*)(myP + r*512 + ((l*8) ^ ((r & 7) << 3)));
      f32x4 o;
      o[0] = bf2f(u.x); o[1] = bf2f(u.y); o[2] = bf2f(u.z); o[3] = bf2f(u.w);
      __builtin_nontemporal_store(o, (f32x4*)(arow0 + (size_t)r*2048 + kt*256 + l*4));
    }
  }

  // ---- ctx store: lane holds ctx[q = g*4+j][d = df*16+li]
  #pragma unroll
  for (int df = 0; df < 4; ++df)
    #pragma unroll
    for (int j = 0; j < 4; ++j)
      ctxb[(size_t)(b*2048 + qt*64 + w*16 + g*4 + j)*1024 + h*64 + df*16 + li]
        = f2bf(pv[df][j]);
}

// ---------------------------------------------------------------- launch
extern "C" void kernel_launch(void* const* d_in, const int* in_sizes, int n_in,
                              void* d_out, int out_size, void* d_ws, size_t ws_size,
                              hipStream_t stream)
{
  const float* X  = (const float*)d_in[0];
  const float* Wq = (const float*)d_in[1];
  const float* bq = (const float*)d_in[2];
  const float* Wk = (const float*)d_in[3];
  const float* bk = (const float*)d_in[4];
  const float* Wv = (const float*)d_in[5];
  const float* bv = (const float*)d_in[6];
  const float* Wo = (const float*)d_in[7];
  const float* bo = (const float*)d_in[8];

  char* ws = (char*)d_ws;
  unsigned short* Xb    = (unsigned short*)(ws);                    // 8 MB
  unsigned short* Qb    = (unsigned short*)(ws + (size_t)( 8u<<20));// 8 MB
  unsigned short* Khead = (unsigned short*)(ws + (size_t)(16u<<20));// 8 MB
  unsigned short* Vt    = (unsigned short*)(ws + (size_t)(24u<<20));// 8 MB
  unsigned short* Cb    = (unsigned short*)(ws + (size_t)(32u<<20));// 8 MB
  unsigned short* Wqb   = (unsigned short*)(ws + (size_t)(40u<<20));// 2 MB
  unsigned short* Wkb   = (unsigned short*)(ws + (size_t)(42u<<20));
  unsigned short* Wvb   = (unsigned short*)(ws + (size_t)(44u<<20));
  unsigned short* Wob   = (unsigned short*)(ws + (size_t)(46u<<20));

  float* out  = (float*)d_out;
  float* attn = out + (size_t)4194304;     // [2][16][2048][2048]

  cvt_bf16<<<4096, 256, 0, stream>>>(X,  Xb,  1048576);
  cvt_bf16<<<1024, 256, 0, stream>>>(Wq, Wqb, 262144);
  cvt_bf16<<<1024, 256, 0, stream>>>(Wk, Wkb, 262144);
  cvt_bf16<<<1024, 256, 0, stream>>>(Wv, Wvb, 262144);
  cvt_bf16<<<1024, 256, 0, stream>>>(Wo, Wob, 262144);

  dim3 qkvgrid(24, 32);
  qkv_gemm<<<qkvgrid, 256, 0, stream>>>(Xb, Wqb, Wkb, Wvb, bq, bk, bv, Qb, Khead, Vt);

  attn_ind<<<dim3(1024), 256, 0, stream>>>(Qb, Khead, Vt, attn, Cb);

  dim3 ggrid(8, 32);
  gemm_bt<<<ggrid, 256, 0, stream>>>(Cb, Wob, bo, out, 4096, 1024, 1024);
}

// Round 20
// 408.402 us; speedup vs baseline: 1.1107x; 1.1107x over previous
//
#include <hip/hip_runtime.h>
#include <hip/hip_bf16.h>
#include <cstdint>

typedef __attribute__((ext_vector_type(4))) float f32x4;
typedef __attribute__((ext_vector_type(8))) short bf16x8;

__device__ __forceinline__ unsigned short f2bf(float f){
  union { float f; unsigned int u; } v; v.f = f;
  unsigned int u = v.u;
  u += 0x7FFFu + ((u >> 16) & 1u);   // round-to-nearest-even
  return (unsigned short)(u >> 16);
}
__device__ __forceinline__ float bf2f(unsigned short s){
  union { unsigned int u; float f; } v; v.u = ((unsigned int)s) << 16;
  return v.f;
}

// ---------------------------------------------------------------- cvt f32->bf16 (X)
__global__ __launch_bounds__(256) void cvt_bf16(const float* __restrict__ in,
                                                unsigned short* __restrict__ out,
                                                int n4){
  int i = blockIdx.x * 256 + threadIdx.x;
  if (i < n4){
    float4 v = ((const float4*)in)[i];
    ushort4 o;
    o.x = f2bf(v.x); o.y = f2bf(v.y); o.z = f2bf(v.z); o.w = f2bf(v.w);
    ((ushort4*)out)[i] = o;
  }
}

// ---------------------------------------------------------------- cvt all 4 weights in one launch
__global__ __launch_bounds__(256) void cvt_w4(const float* __restrict__ W0,
                                              const float* __restrict__ W1,
                                              const float* __restrict__ W2,
                                              const float* __restrict__ W3,
                                              unsigned short* __restrict__ o0,
                                              unsigned short* __restrict__ o1,
                                              unsigned short* __restrict__ o2,
                                              unsigned short* __restrict__ o3){
  const int wi = blockIdx.y;
  const float* in = (wi == 0) ? W0 : (wi == 1) ? W1 : (wi == 2) ? W2 : W3;
  unsigned short* out = (wi == 0) ? o0 : (wi == 1) ? o1 : (wi == 2) ? o2 : o3;
  int i = blockIdx.x * 256 + threadIdx.x;     // 262144 float4 per weight
  float4 v = ((const float4*)in)[i];
  ushort4 o;
  o.x = f2bf(v.x); o.y = f2bf(v.y); o.z = f2bf(v.z); o.w = f2bf(v.w);
  ((ushort4*)out)[i] = o;
}

// ---------------------------------------------------------------- fused QKV GEMM
// widx 0 -> Q row-major; widx 1 -> Khead[bh][key][64]; widx 2 -> Vt[(b*1024+col)][s]
__global__ __launch_bounds__(256) void qkv_gemm(
    const unsigned short* __restrict__ A,
    const unsigned short* __restrict__ W0,
    const unsigned short* __restrict__ W1,
    const unsigned short* __restrict__ W2,
    const float* __restrict__ b0,
    const float* __restrict__ b1,
    const float* __restrict__ b2,
    unsigned short* __restrict__ Qo,
    unsigned short* __restrict__ Khead,
    unsigned short* __restrict__ Vto)
{
  __shared__ unsigned short As[2][128*64];
  __shared__ unsigned short Bs[2][128*64];

  const int K = 1024;
  const int tid = threadIdx.x;
  const int l   = tid & 63;
  const int wid = tid >> 6;
  const int g   = l >> 4;
  const int li  = l & 15;
  const int widx = blockIdx.x >> 3;
  const int m0  = blockIdx.y * 128;
  const int n0  = (blockIdx.x & 7) * 128;
  const int wm  = (wid >> 1) * 64;
  const int wn  = (wid & 1) * 64;
  const int srow = tid >> 3;
  const int sck  = tid & 7;

  const unsigned short* Bw = (widx == 0) ? W0 : ((widx == 1) ? W1 : W2);
  const float* bias        = (widx == 0) ? b0 : ((widx == 1) ? b1 : b2);

  const unsigned short* Ag = A  + (size_t)(m0 + srow) * K + sck * 8;
  const unsigned short* Bg = Bw + (size_t)(n0 + srow) * K + sck * 8;

  f32x4 acc[4][4] = {};
  bf16x8 ra[4], rb[4];
  const int NT = K >> 6;

  #pragma unroll
  for (int r = 0; r < 4; ++r){
    ra[r] = *(const bf16x8*)(Ag + (size_t)(r*32) * K);
    rb[r] = *(const bf16x8*)(Bg + (size_t)(r*32) * K);
  }
  #pragma unroll
  for (int r = 0; r < 4; ++r){
    const int row = srow + r*32;
    const int ck  = sck ^ (row & 7);
    *(bf16x8*)(&As[0][row*64 + ck*8]) = ra[r];
    *(bf16x8*)(&Bs[0][row*64 + ck*8]) = rb[r];
  }
  __syncthreads();

  int cur = 0;
  for (int kt = 0; kt < NT; ++kt){
    if (kt + 1 < NT){
      const int kof = (kt + 1) << 6;
      #pragma unroll
      for (int r = 0; r < 4; ++r){
        ra[r] = *(const bf16x8*)(Ag + (size_t)(r*32) * K + kof);
        rb[r] = *(const bf16x8*)(Bg + (size_t)(r*32) * K + kof);
      }
    }
    #pragma unroll
    for (int kk = 0; kk < 2; ++kk){
      bf16x8 af[4], bfr[4];
      #pragma unroll
      for (int f = 0; f < 4; ++f){
        const int rowa = wm + f*16 + li;
        const int cka  = (kk*4 + g) ^ (rowa & 7);
        af[f] = *(const bf16x8*)(&As[cur][rowa*64 + cka*8]);
        const int rowb = wn + f*16 + li;
        const int ckb  = (kk*4 + g) ^ (rowb & 7);
        bfr[f] = *(const bf16x8*)(&Bs[cur][rowb*64 + ckb*8]);
      }
      #pragma unroll
      for (int fm = 0; fm < 4; ++fm)
        #pragma unroll
        for (int fn = 0; fn < 4; ++fn)
          acc[fm][fn] = __builtin_amdgcn_mfma_f32_16x16x32_bf16(af[fm], bfr[fn], acc[fm][fn], 0, 0, 0);
    }
    __syncthreads();
    if (kt + 1 < NT){
      #pragma unroll
      for (int r = 0; r < 4; ++r){
        const int row = srow + r*32;
        const int ck  = sck ^ (row & 7);
        *(bf16x8*)(&As[cur^1][row*64 + ck*8]) = ra[r];
        *(bf16x8*)(&Bs[cur^1][row*64 + ck*8]) = rb[r];
      }
      __syncthreads();
    }
    cur ^= 1;
  }

  #pragma unroll
  for (int fn = 0; fn < 4; ++fn){
    const int col = n0 + wn + fn*16 + li;
    const float bv = bias[col];
    #pragma unroll
    for (int fm = 0; fm < 4; ++fm){
      #pragma unroll
      for (int j = 0; j < 4; ++j){
        const int row = m0 + wm + fm*16 + g*4 + j;
        const float v = acc[fm][fn][j] + bv;
        const int bb = row >> 11;
        const int s  = row & 2047;
        if (widx == 0){
          Qo[(size_t)row * 1024 + col] = f2bf(v);
        } else if (widx == 1){
          const int hh = col >> 6, dd = col & 63;
          Khead[(((size_t)(bb*16 + hh))*2048 + s)*64 + dd] = f2bf(v);
        } else {
          Vto[((size_t)(bb*1024 + col)) * 2048 + s] = f2bf(v);
        }
      }
    }
  }
}

// ---------------------------------------------------------------- out-proj GEMM (f32 out)
__global__ __launch_bounds__(256) void gemm_bt(
    const unsigned short* __restrict__ A,
    const unsigned short* __restrict__ Bw,
    const float* __restrict__ bias,
    float* __restrict__ outp,
    int M, int N, int K)
{
  __shared__ unsigned short As[2][128*64];
  __shared__ unsigned short Bs[2][128*64];

  const int tid = threadIdx.x;
  const int l   = tid & 63;
  const int wid = tid >> 6;
  const int g   = l >> 4;
  const int li  = l & 15;
  const int m0  = blockIdx.y * 128;
  const int n0  = blockIdx.x * 128;
  const int wm  = (wid >> 1) * 64;
  const int wn  = (wid & 1) * 64;
  const int srow = tid >> 3;
  const int sck  = tid & 7;

  const unsigned short* Ag = A  + (size_t)(m0 + srow) * K + sck * 8;
  const unsigned short* Bg = Bw + (size_t)(n0 + srow) * K + sck * 8;

  f32x4 acc[4][4] = {};
  bf16x8 ra[4], rb[4];
  const int NT = K >> 6;

  #pragma unroll
  for (int r = 0; r < 4; ++r){
    ra[r] = *(const bf16x8*)(Ag + (size_t)(r*32) * K);
    rb[r] = *(const bf16x8*)(Bg + (size_t)(r*32) * K);
  }
  #pragma unroll
  for (int r = 0; r < 4; ++r){
    const int row = srow + r*32;
    const int ck  = sck ^ (row & 7);
    *(bf16x8*)(&As[0][row*64 + ck*8]) = ra[r];
    *(bf16x8*)(&Bs[0][row*64 + ck*8]) = rb[r];
  }
  __syncthreads();

  int cur = 0;
  for (int kt = 0; kt < NT; ++kt){
    if (kt + 1 < NT){
      const int kof = (kt + 1) << 6;
      #pragma unroll
      for (int r = 0; r < 4; ++r){
        ra[r] = *(const bf16x8*)(Ag + (size_t)(r*32) * K + kof);
        rb[r] = *(const bf16x8*)(Bg + (size_t)(r*32) * K + kof);
      }
    }
    #pragma unroll
    for (int kk = 0; kk < 2; ++kk){
      bf16x8 af[4], bfr[4];
      #pragma unroll
      for (int f = 0; f < 4; ++f){
        const int rowa = wm + f*16 + li;
        const int cka  = (kk*4 + g) ^ (rowa & 7);
        af[f] = *(const bf16x8*)(&As[cur][rowa*64 + cka*8]);
        const int rowb = wn + f*16 + li;
        const int ckb  = (kk*4 + g) ^ (rowb & 7);
        bfr[f] = *(const bf16x8*)(&Bs[cur][rowb*64 + ckb*8]);
      }
      #pragma unroll
      for (int fm = 0; fm < 4; ++fm)
        #pragma unroll
        for (int fn = 0; fn < 4; ++fn)
          acc[fm][fn] = __builtin_amdgcn_mfma_f32_16x16x32_bf16(af[fm], bfr[fn], acc[fm][fn], 0, 0, 0);
    }
    __syncthreads();
    if (kt + 1 < NT){
      #pragma unroll
      for (int r = 0; r < 4; ++r){
        const int row = srow + r*32;
        const int ck  = sck ^ (row & 7);
        *(bf16x8*)(&As[cur^1][row*64 + ck*8]) = ra[r];
        *(bf16x8*)(&Bs[cur^1][row*64 + ck*8]) = rb[r];
      }
      __syncthreads();
    }
    cur ^= 1;
  }

  #pragma unroll
  for (int fn = 0; fn < 4; ++fn){
    const int col = n0 + wn + fn*16 + li;
    const float bv = bias[col];
    #pragma unroll
    for (int fm = 0; fm < 4; ++fm){
      #pragma unroll
      for (int j = 0; j < 4; ++j){
        const int row = m0 + wm + fm*16 + g*4 + j;
        outp[(size_t)row * N + col] = acc[fm][fn][j] + bv;
      }
    }
  }
}

// ---------------------------------------------------------------- attn_denom (verified in R13)
// GEMM-shaped: block (kt,bh) x qt handles 128 q-rows x 256 keys. K-tile in LDS.
// Writes partial denominators denomP[kt][bh][q].
__global__ __launch_bounds__(256, 4) void attn_denom(
    const unsigned short* __restrict__ Qb,    // [4096][1024] bf16
    const unsigned short* __restrict__ Khead, // [32][2048][64] bf16
    float* __restrict__ denomP)               // [8][32][2048] f32
{
  __shared__ unsigned short Ks[256*64];       // 32 KB, chunk-swizzled
  char* Kb8 = (char*)Ks;

  const int tid = threadIdx.x;
  const int l   = tid & 63;
  const int w   = tid >> 6;
  const int g   = l >> 4;
  const int li  = l & 15;
  const int kt  = blockIdx.x >> 5;
  const int bh  = blockIdx.x & 31;
  const int qt  = blockIdx.y;
  const int b   = bh >> 4;
  const int h   = bh & 15;

  {
    const unsigned short* Kg = Khead + ((size_t)bh * 2048 + kt*256) * 64;
    #pragma unroll
    for (int p = 0; p < 8; ++p){
      const int key = p*32 + (tid >> 3);
      const int c   = tid & 7;
      const bf16x8 v = *(const bf16x8*)(Kg + (size_t)key * 64 + c*8);
      *(bf16x8*)(Kb8 + key*128 + ((c ^ (key & 7)) * 16)) = v;
    }
  }
  __syncthreads();

  #pragma unroll
  for (int rg = 0; rg < 2; ++rg){
    const int qrow = qt*128 + w*32 + rg*16 + li;
    const size_t qoff = (size_t)(b*2048 + qrow) * 1024 + h*64 + g*8;
    const bf16x8 aq0 = *(const bf16x8*)(Qb + qoff);
    const bf16x8 aq1 = *(const bf16x8*)(Qb + qoff + 32);

    float ls = 0.f;
    #pragma unroll
    for (int cf = 0; cf < 16; ++cf){
      const int key = cf*16 + li;
      const bf16x8 k0 = *(const bf16x8*)(Kb8 + key*128 + (( g    ^ (key & 7)) * 16));
      const bf16x8 k1 = *(const bf16x8*)(Kb8 + key*128 + (((g+4) ^ (key & 7)) * 16));
      f32x4 t = {};
      t = __builtin_amdgcn_mfma_f32_16x16x32_bf16(k0, aq0, t, 0, 0, 0);
      t = __builtin_amdgcn_mfma_f32_16x16x32_bf16(k1, aq1, t, 0, 0, 0);
      ls += __expf(t[0]*0.125f) + __expf(t[1]*0.125f)
          + __expf(t[2]*0.125f) + __expf(t[3]*0.125f);
    }
    ls += __shfl_xor(ls, 16);
    ls += __shfl_xor(ls, 32);
    if (l < 16)
      denomP[((size_t)kt*32 + bh)*2048 + qt*128 + w*32 + rg*16 + l] = ls;
  }
}

// ---------------------------------------------------------------- attn_pass4 (R20)
// 4-way key-split, barrier-free. Grid (128, 32): kt2 = bx>>5 (0..3 key quarter),
// bh = bx&31, qt = by (64 q-rows). 4 independent waves x 16 q-rows. Per wave:
// ONE QK^T over 512 keys (denoms precomputed), normalized bf16 P -> private 8KB
// LDS slab, PV -> ctx partial CP[kt2], attn NT stores. No __syncthreads at all.
__global__ __launch_bounds__(256, 4) void attn_pass4(
    const unsigned short* __restrict__ Qb,    // [4096][1024] bf16
    const unsigned short* __restrict__ Khead, // [32][2048][64] bf16
    const unsigned short* __restrict__ Vt,    // [2048][2048] bf16
    const float* __restrict__ denomP,         // [8][32][2048] f32
    float* __restrict__ attn,                 // [32][2048][2048] f32
    float* __restrict__ CP)                   // [4][32][2048][64] f32
{
  __shared__ __align__(16) unsigned short Pw4[4][16*256];   // 32 KB: private P slabs

  const int tid = threadIdx.x;
  const int l   = tid & 63;
  const int w   = tid >> 6;       // 0..3, independent wave
  const int g   = l >> 4;
  const int li  = l & 15;
  const int kt2 = blockIdx.x >> 5;     // 0..3 key quarter
  const int bh  = blockIdx.x & 31;
  const int qt  = blockIdx.y;          // 0..31
  const int b   = bh >> 4;
  const int h   = bh & 15;

  const int qrow = qt*64 + w*16 + li;
  const size_t qoff = (size_t)(b*2048 + qrow) * 1024 + h*64 + g*8;
  const bf16x8 aq0 = *(const bf16x8*)(Qb + qoff);
  const bf16x8 aq1 = *(const bf16x8*)(Qb + qoff + 32);
  const unsigned short* Kg0 = Khead + (size_t)bh * (2048*64) + g*8;

  // total denominator = sum of the 8 partials
  float dsum = 0.f;
  #pragma unroll
  for (int k2 = 0; k2 < 8; ++k2)
    dsum += denomP[((size_t)k2*32 + bh)*2048 + qrow];
  const float rv = 1.0f / dsum;

  f32x4 pv[4] = {};
  char* myP = (char*)(&Pw4[w][0]);     // 16 rows x 512B
  const int swz = (li & 7) << 3;
  const unsigned short* Vb0 = Vt + (size_t)(b*1024 + h*64) * 2048;
  float* arow0 = attn + ((size_t)bh*2048 + qt*64 + w*16) * 2048;

  #pragma unroll
  for (int t = 0; t < 2; ++t){
    const int kbase = kt2*512 + t*256;    // this tile's first key

    // QK^T -> normalized bf16 P (private slab, same-wave dependency only)
    #pragma unroll
    for (int half = 0; half < 2; ++half){
      bf16x8 bk[16];
      #pragma unroll
      for (int cf = 0; cf < 8; ++cf){
        const unsigned short* kr = Kg0 + (size_t)(kbase + half*128 + cf*16 + li) * 64;
        bk[cf*2]   = *(const bf16x8*)(kr);
        bk[cf*2+1] = *(const bf16x8*)(kr + 32);
      }
      #pragma unroll
      for (int cf = 0; cf < 8; ++cf){
        f32x4 s = {};
        s = __builtin_amdgcn_mfma_f32_16x16x32_bf16(bk[cf*2],   aq0, s, 0, 0, 0);
        s = __builtin_amdgcn_mfma_f32_16x16x32_bf16(bk[cf*2+1], aq1, s, 0, 0, 0);
        ushort4 u;
        u.x = f2bf(__expf(s[0]*0.125f) * rv);
        u.y = f2bf(__expf(s[1]*0.125f) * rv);
        u.z = f2bf(__expf(s[2]*0.125f) * rv);
        u.w = f2bf(__expf(s[3]*0.125f) * rv);
        const int colb = half*256 + cf*32 + g*8;   // byte col within tile
        *(ushort4*)(myP + li*512 + (colb ^ swz)) = u;
      }
    }

    // PV: 2 halves x (16 batched V loads; 4 key-steps x 4 d-frags)
    #pragma unroll
    for (int vh = 0; vh < 2; ++vh){
      bf16x8 vb[16];
      #pragma unroll
      for (int ks = 0; ks < 4; ++ks)
        #pragma unroll
        for (int df = 0; df < 4; ++df)
          vb[ks*4+df] = *(const bf16x8*)(Vb0 + (size_t)(df*16 + li)*2048
                                         + kbase + (vh*4+ks)*32 + g*8);
      #pragma unroll
      for (int ks = 0; ks < 4; ++ks){
        const int colb = (vh*4+ks)*64 + g*16;
        const ushort4 plo = *(const ushort4*)(myP + li*512 + ( colb      ^ swz));
        const ushort4 phi = *(const ushort4*)(myP + li*512 + ((colb + 8) ^ swz));
        bf16x8 pa;
        pa[0] = plo.x; pa[1] = plo.y; pa[2] = plo.z; pa[3] = plo.w;
        pa[4] = phi.x; pa[5] = phi.y; pa[6] = phi.z; pa[7] = phi.w;
        #pragma unroll
        for (int df = 0; df < 4; ++df)
          pv[df] = __builtin_amdgcn_mfma_f32_16x16x32_bf16(pa, vb[ks*4+df], pv[df], 0, 0, 0);
      }
    }

    // attn stores: coalesced readback, 16 x 1KB NT, streamed (no barriers anywhere)
    #pragma unroll
    for (int r = 0; r < 16; ++r){
      const ushort4 u = *(const ushort4*)(myP + r*512 + ((l*8) ^ ((r & 7) << 3)));
      f32x4 o;
      o[0] = bf2f(u.x); o[1] = bf2f(u.y); o[2] = bf2f(u.z); o[3] = bf2f(u.w);
      __builtin_nontemporal_store(o, (f32x4*)(arow0 + (size_t)r*2048 + kbase + l*4));
    }
  }

  // ---- ctx partial: lane holds ctx[q = g*4+j][d = df*16+li]
  #pragma unroll
  for (int df = 0; df < 4; ++df)
    #pragma unroll
    for (int j = 0; j < 4; ++j)
      CP[(((size_t)kt2*32 + bh)*2048 + qt*64 + w*16 + g*4 + j)*64 + df*16 + li]
        = pv[df][j];
}

// ---------------------------------------------------------------- ctx_reduce4
// Cb[b*2048+q][h*64+d] = sum_kt2 CP[kt2][bh][q][d], bf16 out.
__global__ __launch_bounds__(256) void ctx_reduce4(
    const float* __restrict__ CP,
    unsigned short* __restrict__ Cb)
{
  const int idx = blockIdx.x * 256 + threadIdx.x;   // 1,048,576 threads x 4 d
  const int bh  = idx >> 15;
  const int rem = idx & 32767;
  const int q   = rem >> 4;
  const int d4  = (rem & 15) << 2;
  f32x4 s = {};
  #pragma unroll
  for (int k2 = 0; k2 < 4; ++k2){
    const f32x4 v = *(const f32x4*)(CP + (((size_t)k2*32 + bh)*2048 + q)*64 + d4);
    s[0] += v[0]; s[1] += v[1]; s[2] += v[2]; s[3] += v[3];
  }
  const int b = bh >> 4, h = bh & 15;
  ushort4 o;
  o.x = f2bf(s[0]); o.y = f2bf(s[1]); o.z = f2bf(s[2]); o.w = f2bf(s[3]);
  *(ushort4*)(Cb + (size_t)(b*2048 + q)*1024 + h*64 + d4) = o;
}

// ---------------------------------------------------------------- launch
extern "C" void kernel_launch(void* const* d_in, const int* in_sizes, int n_in,
                              void* d_out, int out_size, void* d_ws, size_t ws_size,
                              hipStream_t stream)
{
  const float* X  = (const float*)d_in[0];
  const float* Wq = (const float*)d_in[1];
  const float* bq = (const float*)d_in[2];
  const float* Wk = (const float*)d_in[3];
  const float* bk = (const float*)d_in[4];
  const float* Wv = (const float*)d_in[5];
  const float* bv = (const float*)d_in[6];
  const float* Wo = (const float*)d_in[7];
  const float* bo = (const float*)d_in[8];

  char* ws = (char*)d_ws;
  unsigned short* Xb    = (unsigned short*)(ws);                    // 8 MB
  unsigned short* Qb    = (unsigned short*)(ws + (size_t)( 8u<<20));// 8 MB
  unsigned short* Khead = (unsigned short*)(ws + (size_t)(16u<<20));// 8 MB
  unsigned short* Vt    = (unsigned short*)(ws + (size_t)(24u<<20));// 8 MB
  unsigned short* Cb    = (unsigned short*)(ws + (size_t)(32u<<20));// 8 MB
  unsigned short* Wqb   = (unsigned short*)(ws + (size_t)(40u<<20));// 2 MB
  unsigned short* Wkb   = (unsigned short*)(ws + (size_t)(42u<<20));
  unsigned short* Wvb   = (unsigned short*)(ws + (size_t)(44u<<20));
  unsigned short* Wob   = (unsigned short*)(ws + (size_t)(46u<<20));
  float*          denomP= (float*)(ws + (size_t)(48u<<20));         // 2 MB
  float*          CP    = (float*)(ws + (size_t)(56u<<20));         // 67 MB

  float* out  = (float*)d_out;
  float* attn = out + (size_t)4194304;     // [2][16][2048][2048]

  cvt_bf16<<<4096, 256, 0, stream>>>(X, Xb, 1048576);
  cvt_w4<<<dim3(1024, 4), 256, 0, stream>>>(Wq, Wk, Wv, Wo, Wqb, Wkb, Wvb, Wob);

  dim3 qkvgrid(24, 32);
  qkv_gemm<<<qkvgrid, 256, 0, stream>>>(Xb, Wqb, Wkb, Wvb, bq, bk, bv, Qb, Khead, Vt);

  attn_denom<<<dim3(256, 16), 256, 0, stream>>>(Qb, Khead, denomP);
  attn_pass4<<<dim3(128, 32), 256, 0, stream>>>(Qb, Khead, Vt, denomP, attn, CP);
  ctx_reduce4<<<4096, 256, 0, stream>>>(CP, Cb);

  dim3 ggrid(8, 32);
  gemm_bt<<<ggrid, 256, 0, stream>>>(Cb, Wob, bo, out, 4096, 1024, 1024);
}

// Round 21
// 329.119 us; speedup vs baseline: 1.3783x; 1.2409x over previous
//
#include <hip/hip_runtime.h>
#include <hip/hip_bf16.h>
#include <cstdint>

typedef __attribute__((ext_vector_type(4))) float f32x4;
typedef __attribute__((ext_vector_type(8))) short bf16x8;

__device__ __forceinline__ unsigned short f2bf(float f){
  union { float f; unsigned int u; } v; v.f = f;
  unsigned int u = v.u;
  u += 0x7FFFu + ((u >> 16) & 1u);   // round-to-nearest-even
  return (unsigned short)(u >> 16);
}
__device__ __forceinline__ float bf2f(unsigned short s){
  union { unsigned int u; float f; } v; v.u = ((unsigned int)s) << 16;
  return v.f;
}

// ---------------------------------------------------------------- cvt f32->bf16 (X)
__global__ __launch_bounds__(256) void cvt_bf16(const float* __restrict__ in,
                                                unsigned short* __restrict__ out,
                                                int n4){
  int i = blockIdx.x * 256 + threadIdx.x;
  if (i < n4){
    float4 v = ((const float4*)in)[i];
    ushort4 o;
    o.x = f2bf(v.x); o.y = f2bf(v.y); o.z = f2bf(v.z); o.w = f2bf(v.w);
    ((ushort4*)out)[i] = o;
  }
}

// ---------------------------------------------------------------- cvt all 4 weights in one launch
__global__ __launch_bounds__(256) void cvt_w4(const float* __restrict__ W0,
                                              const float* __restrict__ W1,
                                              const float* __restrict__ W2,
                                              const float* __restrict__ W3,
                                              unsigned short* __restrict__ o0,
                                              unsigned short* __restrict__ o1,
                                              unsigned short* __restrict__ o2,
                                              unsigned short* __restrict__ o3){
  const int wi = blockIdx.y;
  const float* in = (wi == 0) ? W0 : (wi == 1) ? W1 : (wi == 2) ? W2 : W3;
  unsigned short* out = (wi == 0) ? o0 : (wi == 1) ? o1 : (wi == 2) ? o2 : o3;
  int i = blockIdx.x * 256 + threadIdx.x;     // 262144 float4 per weight
  float4 v = ((const float4*)in)[i];
  ushort4 o;
  o.x = f2bf(v.x); o.y = f2bf(v.y); o.z = f2bf(v.z); o.w = f2bf(v.w);
  ((ushort4*)out)[i] = o;
}

// ---------------------------------------------------------------- fused QKV GEMM
// widx 0 -> Q row-major; widx 1 -> Khead[bh][key][64]; widx 2 -> Vt[(b*1024+col)][s]
__global__ __launch_bounds__(256) void qkv_gemm(
    const unsigned short* __restrict__ A,
    const unsigned short* __restrict__ W0,
    const unsigned short* __restrict__ W1,
    const unsigned short* __restrict__ W2,
    const float* __restrict__ b0,
    const float* __restrict__ b1,
    const float* __restrict__ b2,
    unsigned short* __restrict__ Qo,
    unsigned short* __restrict__ Khead,
    unsigned short* __restrict__ Vto)
{
  __shared__ unsigned short As[2][128*64];
  __shared__ unsigned short Bs[2][128*64];

  const int K = 1024;
  const int tid = threadIdx.x;
  const int l   = tid & 63;
  const int wid = tid >> 6;
  const int g   = l >> 4;
  const int li  = l & 15;
  const int widx = blockIdx.x >> 3;
  const int m0  = blockIdx.y * 128;
  const int n0  = (blockIdx.x & 7) * 128;
  const int wm  = (wid >> 1) * 64;
  const int wn  = (wid & 1) * 64;
  const int srow = tid >> 3;
  const int sck  = tid & 7;

  const unsigned short* Bw = (widx == 0) ? W0 : ((widx == 1) ? W1 : W2);
  const float* bias        = (widx == 0) ? b0 : ((widx == 1) ? b1 : b2);

  const unsigned short* Ag = A  + (size_t)(m0 + srow) * K + sck * 8;
  const unsigned short* Bg = Bw + (size_t)(n0 + srow) * K + sck * 8;

  f32x4 acc[4][4] = {};
  bf16x8 ra[4], rb[4];
  const int NT = K >> 6;

  #pragma unroll
  for (int r = 0; r < 4; ++r){
    ra[r] = *(const bf16x8*)(Ag + (size_t)(r*32) * K);
    rb[r] = *(const bf16x8*)(Bg + (size_t)(r*32) * K);
  }
  #pragma unroll
  for (int r = 0; r < 4; ++r){
    const int row = srow + r*32;
    const int ck  = sck ^ (row & 7);
    *(bf16x8*)(&As[0][row*64 + ck*8]) = ra[r];
    *(bf16x8*)(&Bs[0][row*64 + ck*8]) = rb[r];
  }
  __syncthreads();

  int cur = 0;
  for (int kt = 0; kt < NT; ++kt){
    if (kt + 1 < NT){
      const int kof = (kt + 1) << 6;
      #pragma unroll
      for (int r = 0; r < 4; ++r){
        ra[r] = *(const bf16x8*)(Ag + (size_t)(r*32) * K + kof);
        rb[r] = *(const bf16x8*)(Bg + (size_t)(r*32) * K + kof);
      }
    }
    #pragma unroll
    for (int kk = 0; kk < 2; ++kk){
      bf16x8 af[4], bfr[4];
      #pragma unroll
      for (int f = 0; f < 4; ++f){
        const int rowa = wm + f*16 + li;
        const int cka  = (kk*4 + g) ^ (rowa & 7);
        af[f] = *(const bf16x8*)(&As[cur][rowa*64 + cka*8]);
        const int rowb = wn + f*16 + li;
        const int ckb  = (kk*4 + g) ^ (rowb & 7);
        bfr[f] = *(const bf16x8*)(&Bs[cur][rowb*64 + ckb*8]);
      }
      #pragma unroll
      for (int fm = 0; fm < 4; ++fm)
        #pragma unroll
        for (int fn = 0; fn < 4; ++fn)
          acc[fm][fn] = __builtin_amdgcn_mfma_f32_16x16x32_bf16(af[fm], bfr[fn], acc[fm][fn], 0, 0, 0);
    }
    __syncthreads();
    if (kt + 1 < NT){
      #pragma unroll
      for (int r = 0; r < 4; ++r){
        const int row = srow + r*32;
        const int ck  = sck ^ (row & 7);
        *(bf16x8*)(&As[cur^1][row*64 + ck*8]) = ra[r];
        *(bf16x8*)(&Bs[cur^1][row*64 + ck*8]) = rb[r];
      }
      __syncthreads();
    }
    cur ^= 1;
  }

  #pragma unroll
  for (int fn = 0; fn < 4; ++fn){
    const int col = n0 + wn + fn*16 + li;
    const float bv = bias[col];
    #pragma unroll
    for (int fm = 0; fm < 4; ++fm){
      #pragma unroll
      for (int j = 0; j < 4; ++j){
        const int row = m0 + wm + fm*16 + g*4 + j;
        const float v = acc[fm][fn][j] + bv;
        const int bb = row >> 11;
        const int s  = row & 2047;
        if (widx == 0){
          Qo[(size_t)row * 1024 + col] = f2bf(v);
        } else if (widx == 1){
          const int hh = col >> 6, dd = col & 63;
          Khead[(((size_t)(bb*16 + hh))*2048 + s)*64 + dd] = f2bf(v);
        } else {
          Vto[((size_t)(bb*1024 + col)) * 2048 + s] = f2bf(v);
        }
      }
    }
  }
}

// ---------------------------------------------------------------- out-proj GEMM (f32 out)
__global__ __launch_bounds__(256) void gemm_bt(
    const unsigned short* __restrict__ A,
    const unsigned short* __restrict__ Bw,
    const float* __restrict__ bias,
    float* __restrict__ outp,
    int M, int N, int K)
{
  __shared__ unsigned short As[2][128*64];
  __shared__ unsigned short Bs[2][128*64];

  const int tid = threadIdx.x;
  const int l   = tid & 63;
  const int wid = tid >> 6;
  const int g   = l >> 4;
  const int li  = l & 15;
  const int m0  = blockIdx.y * 128;
  const int n0  = blockIdx.x * 128;
  const int wm  = (wid >> 1) * 64;
  const int wn  = (wid & 1) * 64;
  const int srow = tid >> 3;
  const int sck  = tid & 7;

  const unsigned short* Ag = A  + (size_t)(m0 + srow) * K + sck * 8;
  const unsigned short* Bg = Bw + (size_t)(n0 + srow) * K + sck * 8;

  f32x4 acc[4][4] = {};
  bf16x8 ra[4], rb[4];
  const int NT = K >> 6;

  #pragma unroll
  for (int r = 0; r < 4; ++r){
    ra[r] = *(const bf16x8*)(Ag + (size_t)(r*32) * K);
    rb[r] = *(const bf16x8*)(Bg + (size_t)(r*32) * K);
  }
  #pragma unroll
  for (int r = 0; r < 4; ++r){
    const int row = srow + r*32;
    const int ck  = sck ^ (row & 7);
    *(bf16x8*)(&As[0][row*64 + ck*8]) = ra[r];
    *(bf16x8*)(&Bs[0][row*64 + ck*8]) = rb[r];
  }
  __syncthreads();

  int cur = 0;
  for (int kt = 0; kt < NT; ++kt){
    if (kt + 1 < NT){
      const int kof = (kt + 1) << 6;
      #pragma unroll
      for (int r = 0; r < 4; ++r){
        ra[r] = *(const bf16x8*)(Ag + (size_t)(r*32) * K + kof);
        rb[r] = *(const bf16x8*)(Bg + (size_t)(r*32) * K + kof);
      }
    }
    #pragma unroll
    for (int kk = 0; kk < 2; ++kk){
      bf16x8 af[4], bfr[4];
      #pragma unroll
      for (int f = 0; f < 4; ++f){
        const int rowa = wm + f*16 + li;
        const int cka  = (kk*4 + g) ^ (rowa & 7);
        af[f] = *(const bf16x8*)(&As[cur][rowa*64 + cka*8]);
        const int rowb = wn + f*16 + li;
        const int ckb  = (kk*4 + g) ^ (rowb & 7);
        bfr[f] = *(const bf16x8*)(&Bs[cur][rowb*64 + ckb*8]);
      }
      #pragma unroll
      for (int fm = 0; fm < 4; ++fm)
        #pragma unroll
        for (int fn = 0; fn < 4; ++fn)
          acc[fm][fn] = __builtin_amdgcn_mfma_f32_16x16x32_bf16(af[fm], bfr[fn], acc[fm][fn], 0, 0, 0);
    }
    __syncthreads();
    if (kt + 1 < NT){
      #pragma unroll
      for (int r = 0; r < 4; ++r){
        const int row = srow + r*32;
        const int ck  = sck ^ (row & 7);
        *(bf16x8*)(&As[cur^1][row*64 + ck*8]) = ra[r];
        *(bf16x8*)(&Bs[cur^1][row*64 + ck*8]) = rb[r];
      }
      __syncthreads();
    }
    cur ^= 1;
  }

  #pragma unroll
  for (int fn = 0; fn < 4; ++fn){
    const int col = n0 + wn + fn*16 + li;
    const float bv = bias[col];
    #pragma unroll
    for (int fm = 0; fm < 4; ++fm){
      #pragma unroll
      for (int j = 0; j < 4; ++j){
        const int row = m0 + wm + fm*16 + g*4 + j;
        outp[(size_t)row * N + col] = acc[fm][fn][j] + bv;
      }
    }
  }
}

// ---------------------------------------------------------------- attn_all (R16 verbatim — measured best)
// 512 threads = 8 waves, producer/consumer split. Compute waves 0-3 own 16 q-rows each
// (QK^T -> normalized bf16 P -> double-buffered LDS -> PV in registers). Store waves 4-7
// read partner's P slab from the previous tile and issue all attn NT stores.
// Pass A (denominators) split across all 8 waves by tile parity.
__global__ __launch_bounds__(512, 2) void attn_all(
    const unsigned short* __restrict__ Qb,    // [4096][1024] bf16
    const unsigned short* __restrict__ Khead, // [32][2048][64] bf16
    const unsigned short* __restrict__ Vt,    // [2048][2048] bf16
    float* __restrict__ attn,                 // [32][2048][2048] f32
    unsigned short* __restrict__ ctxb)        // [4096][1024] bf16
{
  __shared__ __align__(16) char Kb8[256*144];                 // 36 KB swizzled K tile
  __shared__ __align__(16) unsigned short Pw4[4][2][16*256];  // 64 KB double-buffered P
  __shared__ float red[128];                                  // 8 waves x 16 rows

  const int tid = threadIdx.x;
  const int l   = tid & 63;
  const int w   = tid >> 6;       // 0..7
  const int cw  = w & 3;          // q-group
  const int g   = l >> 4;
  const int li  = l & 15;
  const int bh  = blockIdx.x & 31;    // same-bh blocks land on one XCD (stride-32 grid)
  const int qt  = blockIdx.x >> 5;    // 0..31
  const int b   = bh >> 4;
  const int h   = bh & 15;

  const int qrow = qt*64 + cw*16 + li;
  const size_t qoff = (size_t)(b*2048 + qrow) * 1024 + h*64 + g*8;
  const bf16x8 aq0 = *(const bf16x8*)(Qb + qoff);
  const bf16x8 aq1 = *(const bf16x8*)(Qb + qoff + 32);
  const unsigned short* Kg0 = Khead + (size_t)bh * (2048*64);

  // ---- pass A: denominators; wave w handles tiles with parity (w>>2)
  const int parity = w >> 2;
  float ls = 0.f;
  for (int kt = 0; kt < 8; ++kt){
    __syncthreads();
    {
      const unsigned short* Kg = Kg0 + (size_t)kt * (256*64);
      #pragma unroll
      for (int p = 0; p < 4; ++p){
        const int key = p*64 + (tid >> 3);
        const int c   = tid & 7;
        const bf16x8 v = *(const bf16x8*)(Kg + (size_t)key*64 + c*8);
        *(bf16x8*)(Kb8 + key*144 + ((c ^ (key & 7)) * 16)) = v;
      }
    }
    __syncthreads();
    if ((kt & 1) == parity){
      #pragma unroll
      for (int cf = 0; cf < 16; ++cf){
        const int key = cf*16 + li;
        const bf16x8 k0 = *(const bf16x8*)(Kb8 + key*144 + (( g    ^ (key & 7)) * 16));
        const bf16x8 k1 = *(const bf16x8*)(Kb8 + key*144 + (((g+4) ^ (key & 7)) * 16));
        f32x4 t = {};
        t = __builtin_amdgcn_mfma_f32_16x16x32_bf16(k0, aq0, t, 0, 0, 0);
        t = __builtin_amdgcn_mfma_f32_16x16x32_bf16(k1, aq1, t, 0, 0, 0);
        ls += __expf(t[0]*0.125f) + __expf(t[1]*0.125f)
            + __expf(t[2]*0.125f) + __expf(t[3]*0.125f);
      }
    }
  }
  ls += __shfl_xor(ls, 16);
  ls += __shfl_xor(ls, 32);
  if (l < 16) red[w*16 + l] = ls;
  __syncthreads();
  const float rv = 1.0f / (red[cw*16 + li] + red[(cw+4)*16 + li]);   // full denom

  // ---- pass B: compute waves produce P + PV; store waves drain attn
  f32x4 pv[4] = {};
  const int swz = (li & 7) << 3;
  const unsigned short* Vb0 = Vt + (size_t)(b*1024 + h*64) * 2048;
  float* arow0 = attn + ((size_t)bh*2048 + qt*64 + cw*16) * 2048;

  for (int kt = 0; kt < 8; ++kt){
    __syncthreads();                      // prev compute done with Kb8; P[kt-1] published
    {
      const unsigned short* Kg = Kg0 + (size_t)kt * (256*64);
      #pragma unroll
      for (int p = 0; p < 4; ++p){
        const int key = p*64 + (tid >> 3);
        const int c   = tid & 7;
        const bf16x8 v = *(const bf16x8*)(Kg + (size_t)key*64 + c*8);
        *(bf16x8*)(Kb8 + key*144 + ((c ^ (key & 7)) * 16)) = v;
      }
    }
    __syncthreads();

    if (w < 4){
      char* myP = (char*)(&Pw4[cw][kt & 1][0]);     // 16 rows x 512B
      // QK^T -> normalized bf16 P
      #pragma unroll
      for (int cf = 0; cf < 16; ++cf){
        const int key = cf*16 + li;
        const bf16x8 k0 = *(const bf16x8*)(Kb8 + key*144 + (( g    ^ (key & 7)) * 16));
        const bf16x8 k1 = *(const bf16x8*)(Kb8 + key*144 + (((g+4) ^ (key & 7)) * 16));
        f32x4 t = {};
        t = __builtin_amdgcn_mfma_f32_16x16x32_bf16(k0, aq0, t, 0, 0, 0);
        t = __builtin_amdgcn_mfma_f32_16x16x32_bf16(k1, aq1, t, 0, 0, 0);
        ushort4 u;
        u.x = f2bf(__expf(t[0]*0.125f) * rv);
        u.y = f2bf(__expf(t[1]*0.125f) * rv);
        u.z = f2bf(__expf(t[2]*0.125f) * rv);
        u.w = f2bf(__expf(t[3]*0.125f) * rv);
        *(ushort4*)(myP + li*512 + ((cf*32 + g*8) ^ swz)) = u;
      }
      // PV from own fresh P (same-wave LDS dependency)
      #pragma unroll
      for (int vh = 0; vh < 2; ++vh){
        bf16x8 vb[16];
        #pragma unroll
        for (int ks = 0; ks < 4; ++ks)
          #pragma unroll
          for (int df = 0; df < 4; ++df)
            vb[ks*4+df] = *(const bf16x8*)(Vb0 + (size_t)(df*16 + li)*2048
                                           + kt*256 + (vh*4+ks)*32 + g*8);
        #pragma unroll
        for (int ks = 0; ks < 4; ++ks){
          const int colb = (vh*4+ks)*64 + g*16;
          const ushort4 plo = *(const ushort4*)(myP + li*512 + ( colb      ^ swz));
          const ushort4 phi = *(const ushort4*)(myP + li*512 + ((colb + 8) ^ swz));
          bf16x8 pa;
          pa[0] = plo.x; pa[1] = plo.y; pa[2] = plo.z; pa[3] = plo.w;
          pa[4] = phi.x; pa[5] = phi.y; pa[6] = phi.z; pa[7] = phi.w;
          #pragma unroll
          for (int df = 0; df < 4; ++df)
            pv[df] = __builtin_amdgcn_mfma_f32_16x16x32_bf16(pa, vb[ks*4+df], pv[df], 0, 0, 0);
        }
      }
    } else if (kt > 0){
      // store wave: drain partner's previous tile (other P buffer)
      const char* pP = (const char*)(&Pw4[cw][(kt-1) & 1][0]);
      #pragma unroll
      for (int r = 0; r < 16; ++r){
        const ushort4 u = *(const ushort4*)(pP + r*512 + ((l*8) ^ ((r & 7) << 3)));
        f32x4 o;
        o[0] = bf2f(u.x); o[1] = bf2f(u.y); o[2] = bf2f(u.z); o[3] = bf2f(u.w);
        __builtin_nontemporal_store(o, (f32x4*)(arow0 + (size_t)r*2048 + (kt-1)*256 + l*4));
      }
    }
  }

  __syncthreads();                         // P[7] published
  if (w >= 4){
    const char* pP = (const char*)(&Pw4[cw][1][0]);   // tile 7 lives in buf 1
    #pragma unroll
    for (int r = 0; r < 16; ++r){
      const ushort4 u = *(const ushort4*)(pP + r*512 + ((l*8) ^ ((r & 7) << 3)));
      f32x4 o;
      o[0] = bf2f(u.x); o[1] = bf2f(u.y); o[2] = bf2f(u.z); o[3] = bf2f(u.w);
      __builtin_nontemporal_store(o, (f32x4*)(arow0 + (size_t)r*2048 + 7*256 + l*4));
    }
  } else {
    // ctx store: lane holds ctx[q = g*4+j][d = df*16+li]
    #pragma unroll
    for (int df = 0; df < 4; ++df)
      #pragma unroll
      for (int j = 0; j < 4; ++j)
        ctxb[(size_t)(b*2048 + qt*64 + cw*16 + g*4 + j)*1024 + h*64 + df*16 + li]
          = f2bf(pv[df][j]);
  }
}

// ---------------------------------------------------------------- launch
extern "C" void kernel_launch(void* const* d_in, const int* in_sizes, int n_in,
                              void* d_out, int out_size, void* d_ws, size_t ws_size,
                              hipStream_t stream)
{
  const float* X  = (const float*)d_in[0];
  const float* Wq = (const float*)d_in[1];
  const float* bq = (const float*)d_in[2];
  const float* Wk = (const float*)d_in[3];
  const float* bk = (const float*)d_in[4];
  const float* Wv = (const float*)d_in[5];
  const float* bv = (const float*)d_in[6];
  const float* Wo = (const float*)d_in[7];
  const float* bo = (const float*)d_in[8];

  char* ws = (char*)d_ws;
  unsigned short* Xb    = (unsigned short*)(ws);                    // 8 MB
  unsigned short* Qb    = (unsigned short*)(ws + (size_t)( 8u<<20));// 8 MB
  unsigned short* Khead = (unsigned short*)(ws + (size_t)(16u<<20));// 8 MB
  unsigned short* Vt    = (unsigned short*)(ws + (size_t)(24u<<20));// 8 MB
  unsigned short* Cb    = (unsigned short*)(ws + (size_t)(32u<<20));// 8 MB
  unsigned short* Wqb   = (unsigned short*)(ws + (size_t)(40u<<20));// 2 MB
  unsigned short* Wkb   = (unsigned short*)(ws + (size_t)(42u<<20));
  unsigned short* Wvb   = (unsigned short*)(ws + (size_t)(44u<<20));
  unsigned short* Wob   = (unsigned short*)(ws + (size_t)(46u<<20));

  float* out  = (float*)d_out;
  float* attn = out + (size_t)4194304;     // [2][16][2048][2048]

  cvt_bf16<<<4096, 256, 0, stream>>>(X, Xb, 1048576);
  cvt_w4<<<dim3(1024, 4), 256, 0, stream>>>(Wq, Wk, Wv, Wo, Wqb, Wkb, Wvb, Wob);

  dim3 qkvgrid(24, 32);
  qkv_gemm<<<qkvgrid, 256, 0, stream>>>(Xb, Wqb, Wkb, Wvb, bq, bk, bv, Qb, Khead, Vt);

  attn_all<<<dim3(1024), 512, 0, stream>>>(Qb, Khead, Vt, attn, Cb);

  dim3 ggrid(8, 32);
  gemm_bt<<<ggrid, 256, 0, stream>>>(Cb, Wob, bo, out, 4096, 1024, 1024);
}